// Round 1
// baseline (103.016 us; speedup 1.0000x reference)
//
#include <hip/hip_runtime.h>
#include <math.h>

#define NQ 10
#define BATCHN 8192

// ---------------------------------------------------------------------------
// Flag pre-pass: flag = any(inputs > 1.0f)  (== inputs.max() > 1.0)
// ---------------------------------------------------------------------------
__global__ __launch_bounds__(256) void flag_kernel(const float* __restrict__ in,
                                                   int n, int* __restrict__ flag) {
    int i = blockIdx.x * blockDim.x + threadIdx.x;
    bool pred = (i < n) && (in[i] > 1.0f);
    if (__any(pred)) {
        if ((threadIdx.x & 63) == 0) atomicOr(flag, 1);
    }
}

// ---------------------------------------------------------------------------
// Main kernel: one wave (64 lanes) per batch element; 16 complex amps/lane.
// Index k (10 bits): bits 0..3 = register index r, bits 4..9 = lane index l.
// Qubit q acts on bit position p = 9-q.
// First E folded into init (phases at j = gray(k) = k ^ (k>>1)).
// Second E folded into final pairing (t, t^768) -> lane ^ 48.
// ---------------------------------------------------------------------------
__global__ __launch_bounds__(256) void qsim_kernel(const float* __restrict__ in,
                                                   const float* __restrict__ w,
                                                   const int* __restrict__ flag,
                                                   float* __restrict__ out) {
    const int lane = threadIdx.x & 63;
    const int wid  = threadIdx.x >> 6;
    const int b    = blockIdx.x * 4 + wid;

    // ---- load this batch element's 10 inputs, broadcast via shuffles ----
    float xv = 0.0f;
    if (lane < NQ) xv = in[b * NQ + lane];
    if (*flag) xv = atanf(xv);          // uniform branch
    float x[NQ];
#pragma unroll
    for (int q = 0; q < NQ; ++q) x[q] = __shfl(xv, q, 64);

    float Qs = 0.0f;
#pragma unroll
    for (int q = 0; q < NQ; ++q) Qs += x[q] * x[q];

    // ---- initial state: amp[k] = 2^-5 * exp(i*pi*(S + (S^2 - Q)/2)),
    //      S evaluated at j = gray(k). j bits 4..9 depend only on lane. ----
    const int jh = (lane ^ (lane >> 1)) & 63;   // j bits 4..9 (bit i -> qubit 5-i)
    float Sh = 0.0f;
#pragma unroll
    for (int i = 0; i < 6; ++i) Sh += ((jh >> i) & 1) ? x[5 - i] : -x[5 - i];

    float re[16], im[16];
#pragma unroll
    for (int r = 0; r < 16; ++r) {
        // j bits 0..3:  bit p = r_p ^ r_{p+1} (p<3),  bit3 = r3 ^ lane0
        const int jl = (r ^ (r >> 1)) ^ ((lane & 1) << 3);
        float S = Sh;
#pragma unroll
        for (int i = 0; i < 4; ++i) S += ((jl >> i) & 1) ? x[9 - i] : -x[9 - i];
        const float th = 3.14159265358979f * S
                       + 1.57079632679490f * (S * S - Qs);
        float sn, cs;
        __sincosf(th, &sn, &cs);
        re[r] = 0.03125f * cs;
        im[r] = 0.03125f * sn;
    }

    // ---- apply R = tensor_q  Rx(2*pi*w[3+q]) * Rz(2*pi*w[13+q]) ----
    // g00=(cx*cz,-cx*sz) g01=(sx*sz,-sx*cz) g10=(-sx*sz,-sx*cz) g11=(cx*cz,cx*sz)
#pragma unroll
    for (int q = 0; q < NQ; ++q) {
        float sx, cx, sz, cz;
        __sincosf(3.14159265358979f * w[3 + q],  &sx, &cx);
        __sincosf(3.14159265358979f * w[13 + q], &sz, &cz);
        const float g00r =  cx * cz, g00i = -cx * sz;
        const float g01r =  sx * sz, g01i = -sx * cz;
        const float g10r = -sx * sz, g10i = -sx * cz;
        const float g11r =  cx * cz, g11i =  cx * sz;

        const int p = 9 - q;            // bit position this gate acts on
        if (p >= 4) {
            // lane-bit butterfly via shuffle
            const int m = 1 << (p - 4);
            const bool hi = (lane & m) != 0;
            const float car = hi ? g11r : g00r, cai = hi ? g11i : g00i;
            const float cbr = hi ? g10r : g01r, cbi = hi ? g10i : g01i;
#pragma unroll
            for (int r = 0; r < 16; ++r) {
                const float pr = __shfl_xor(re[r], m, 64);
                const float pi = __shfl_xor(im[r], m, 64);
                const float ar = re[r], ai = im[r];
                re[r] = car * ar - cai * ai + cbr * pr - cbi * pi;
                im[r] = car * ai + cai * ar + cbr * pi + cbi * pr;
            }
        } else {
            // register-bit butterfly, fully local
            const int m = 1 << p;
#pragma unroll
            for (int r = 0; r < 16; ++r) {
                if (!(r & m)) {
                    const int r2 = r | m;
                    const float ar = re[r],  ai = im[r];
                    const float br = re[r2], bi = im[r2];
                    re[r]  = g00r * ar - g00i * ai + g01r * br - g01i * bi;
                    im[r]  = g00r * ai + g00i * ar + g01r * bi + g01i * br;
                    re[r2] = g10r * ar - g10i * ai + g11r * br - g11i * bi;
                    im[r2] = g10r * ai + g10i * ar + g11r * bi + g11i * br;
                }
            }
        }
    }

    // ---- final Ry(2*pi*(w0+w1+w2)) on qubit 0 through second E:
    //      pairs (t, t^768) -> lane ^ 48;  measurement sign = bit9 = lane bit5.
    float sf, cf;
    __sincosf(3.14159265358979f * (w[0] + w[1] + w[2]), &sf, &cf);
    const bool hi9 = (lane & 32) != 0;
    float acc = 0.0f;
#pragma unroll
    for (int r = 0; r < 16; ++r) {
        const float pr = __shfl_xor(re[r], 48, 64);
        const float pi = __shfl_xor(im[r], 48, 64);
        float nr, ni;
        if (!hi9) {   // lower-half output amp: u = cf*a - sf*b  (sign -1)
            nr = cf * re[r] - sf * pr;
            ni = cf * im[r] - sf * pi;
        } else {      // upper-half output amp: v = sf*a + cf*b  (sign +1)
            nr = sf * pr + cf * re[r];
            ni = sf * pi + cf * im[r];
        }
        const float p2 = nr * nr + ni * ni;
        acc += hi9 ? p2 : -p2;
    }

    // ---- wave reduction ----
#pragma unroll
    for (int m = 1; m < 64; m <<= 1) acc += __shfl_xor(acc, m, 64);
    if (lane == 0) out[b] = acc;
}

extern "C" void kernel_launch(void* const* d_in, const int* in_sizes, int n_in,
                              void* d_out, int out_size, void* d_ws, size_t ws_size,
                              hipStream_t stream) {
    const float* inputs = (const float*)d_in[0];   // (8192, 10) float32
    const float* weight = (const float*)d_in[1];   // (23,) float32
    // d_in[2] = entangle_matrix — analytically folded (Gray-code map), unused.
    float* out = (float*)d_out;                    // (8192,) float32
    int* flag = (int*)d_ws;

    const int n_elems = BATCHN * NQ;
    hipMemsetAsync(flag, 0, sizeof(int), stream);
    flag_kernel<<<(n_elems + 255) / 256, 256, 0, stream>>>(inputs, n_elems, flag);
    qsim_kernel<<<BATCHN / 4, 256, 0, stream>>>(inputs, weight, flag, out);
}